// Round 2
// baseline (211.040 us; speedup 1.0000x reference)
//
#include <hip/hip_runtime.h>

#define B_TOTAL 16384
#define F_DIM 512
#define H_DIM 256
#define E_NUM 8
#define OUT_COLS 32
#define DA 8
#define TM 16                 // samples per block (one 16-wide MFMA n-tile)
#define HSTRIDE (H_DIM + 8)   // 264 halves: rows 16B-aligned, 528B stride

typedef __attribute__((ext_vector_type(8))) _Float16 half8;
typedef __attribute__((ext_vector_type(4))) _Float16 half4;
typedef __attribute__((ext_vector_type(4))) float float4v;

// ---------------- bucket samples by expert (block-aggregated atomics) ----------------
// 16384 atomics/8 addrs -> 512 atomics/8 addrs: one global atomicAdd per (block, expert).
__global__ void k_bucket(const int* __restrict__ act, int* __restrict__ counts,
                         int* __restrict__ idxbuf) {
  __shared__ int wcnt[4][E_NUM];
  __shared__ int wbase[4][E_NUM];
  int t = threadIdx.x;
  int lane = t & 63, wave = t >> 6;
  int b = blockIdx.x * 256 + t;
  int e = act[b] & 7;

  unsigned long long mymask = 0;
#pragma unroll
  for (int v = 0; v < E_NUM; ++v) {
    unsigned long long m = __ballot(e == v);
    if (lane == 0) wcnt[wave][v] = (int)__popcll(m);
    if (e == v) mymask = m;
  }
  int rank = (int)__popcll(mymask & ((1ull << lane) - 1ull));
  __syncthreads();
  if (t < E_NUM) {
    int c0 = wcnt[0][t], c1 = wcnt[1][t], c2 = wcnt[2][t], c3 = wcnt[3][t];
    int base = atomicAdd(&counts[t], c0 + c1 + c2 + c3);
    wbase[0][t] = base;
    wbase[1][t] = base + c0;
    wbase[2][t] = base + c0 + c1;
    wbase[3][t] = base + c0 + c1 + c2;
  }
  __syncthreads();
  idxbuf[e * B_TOTAL + wbase[wave][e] + rank] = b;
}

// ---------------- transpose + fp32->fp16 convert: (E,K,N) -> (E,N,K) ----------------
template <int K, int N>
__global__ void k_transpose(const float* __restrict__ src, _Float16* __restrict__ dst) {
  __shared__ float tile[32][33];
  int e = blockIdx.z;
  const float* S = src + (size_t)e * K * N;
  _Float16* D = dst + (size_t)e * N * K;
  int k0 = blockIdx.x * 32, n0 = blockIdx.y * 32;
  int tx = threadIdx.x & 31, ty = threadIdx.x >> 5;  // 32x8
#pragma unroll
  for (int r = 0; r < 32; r += 8)
    tile[ty + r][tx] = S[(size_t)(k0 + ty + r) * N + (n0 + tx)];
  __syncthreads();
#pragma unroll
  for (int r = 0; r < 32; r += 8)
    D[(size_t)(n0 + ty + r) * K + (k0 + tx)] = (_Float16)tile[tx][ty + r];
}

// ---------------- W3: (E,256,32) -> (E,16,256) fp16, rows 8..15 zero ----------------
__global__ void k_w3prep(const float* __restrict__ W3, _Float16* __restrict__ W3t) {
  int e = blockIdx.x;
  int k = threadIdx.x;  // 0..255
#pragma unroll
  for (int o = 0; o < 16; ++o) {
    float v = (o < DA) ? W3[((size_t)e * H_DIM + k) * OUT_COLS + o] : 0.f;
    W3t[((size_t)e * 16 + o) * H_DIM + k] = (_Float16)v;
  }
}

// ---------------- fused 3-layer expert MLP, 16-sample blocks ----------------
// 4 waves/block; wave w owns hidden rows [64w, 64w+64) for L1/L2.
// ~1024 active blocks -> 4 blocks/CU (VGPR<=128 via launch_bounds), 16 waves/CU.
__global__ __launch_bounds__(256, 4) void k_mlp(
    const float* __restrict__ X,
    const _Float16* __restrict__ W1t,
    const _Float16* __restrict__ W2t,
    const _Float16* __restrict__ W3t,
    const float* __restrict__ b1,
    const float* __restrict__ b2,
    const float* __restrict__ b3,
    const int* __restrict__ counts,
    const int* __restrict__ idxbuf,
    float* __restrict__ out)
{
  int e = blockIdx.y;
  int cnt = counts[e];
  int tile0 = blockIdx.x * TM;
  if (tile0 >= cnt) return;

  __shared__ _Float16 H1s[TM][HSTRIDE];
  __shared__ _Float16 H2s[TM][HSTRIDE];
  __shared__ float bias1[H_DIM];
  __shared__ float bias2[H_DIM];
  __shared__ float bias3[16];

  int t = threadIdx.x;
  bias1[t] = b1[e * H_DIM + t];
  bias2[t] = b2[e * H_DIM + t];
  if (t < 16) bias3[t] = (t < DA) ? b3[e * OUT_COLS + t] : 0.f;

  int lane = t & 63;
  int wave = t >> 6;
  int quad = lane >> 4;
  int l16 = lane & 15;

  int si = tile0 + l16;
  int sclamp = si < cnt ? si : (cnt - 1);
  int row = idxbuf[e * B_TOTAL + sclamp];
  const float* xrow = X + (size_t)row * F_DIM;
  __syncthreads();  // biases staged

  const float4v vzero = {0.f, 0.f, 0.f, 0.f};
  float4v acc[4];
#pragma unroll
  for (int mt = 0; mt < 4; ++mt) acc[mt] = vzero;

  int hbase = wave * 64;
  int kq = quad * 8;

  // ======== Layer 1: H1^T[h][s] = sum_k W1t[h][k] * X[s][k] ========
  {
    const _Float16* wb = W1t + ((size_t)e * H_DIM + hbase + l16) * F_DIM;
#pragma unroll 4
    for (int kb = 0; kb < F_DIM; kb += 32) {
      int kofs = kb + kq;
      float4v x0 = *(const float4v*)(xrow + kofs);
      float4v x1 = *(const float4v*)(xrow + kofs + 4);
      half8 bfrag;
      bfrag[0] = (_Float16)x0.x; bfrag[1] = (_Float16)x0.y;
      bfrag[2] = (_Float16)x0.z; bfrag[3] = (_Float16)x0.w;
      bfrag[4] = (_Float16)x1.x; bfrag[5] = (_Float16)x1.y;
      bfrag[6] = (_Float16)x1.z; bfrag[7] = (_Float16)x1.w;
#pragma unroll
      for (int mt = 0; mt < 4; ++mt) {
        half8 afrag = *(const half8*)(wb + (size_t)mt * 16 * F_DIM + kofs);
        acc[mt] = __builtin_amdgcn_mfma_f32_16x16x32_f16(afrag, bfrag, acc[mt], 0, 0, 0);
      }
    }
#pragma unroll
    for (int mt = 0; mt < 4; ++mt) {
      int h0 = hbase + mt * 16 + quad * 4;
      float4v bb = *(const float4v*)&bias1[h0];
      half4 hv;
#pragma unroll
      for (int r = 0; r < 4; ++r) {
        float v = acc[mt][r] + bb[r];
        hv[r] = (_Float16)(v > 0.f ? v : 0.f);
      }
      *(half4*)&H1s[l16][h0] = hv;
    }
  }
  __syncthreads();

  // ======== Layer 2: H2^T[h][s] = sum_k W2t[h][k] * H1[s][k] ========
#pragma unroll
  for (int mt = 0; mt < 4; ++mt) acc[mt] = vzero;
  {
    const _Float16* wb = W2t + ((size_t)e * H_DIM + hbase + l16) * H_DIM;
#pragma unroll 4
    for (int kb = 0; kb < H_DIM; kb += 32) {
      int kofs = kb + kq;
      half8 bfrag = *(const half8*)&H1s[l16][kofs];
#pragma unroll
      for (int mt = 0; mt < 4; ++mt) {
        half8 afrag = *(const half8*)(wb + (size_t)mt * 16 * H_DIM + kofs);
        acc[mt] = __builtin_amdgcn_mfma_f32_16x16x32_f16(afrag, bfrag, acc[mt], 0, 0, 0);
      }
    }
#pragma unroll
    for (int mt = 0; mt < 4; ++mt) {
      int h0 = hbase + mt * 16 + quad * 4;
      float4v bb = *(const float4v*)&bias2[h0];
      half4 hv;
#pragma unroll
      for (int r = 0; r < 4; ++r) {
        float v = acc[mt][r] + bb[r];
        hv[r] = (_Float16)(v > 0.f ? v : 0.f);
      }
      *(half4*)&H2s[l16][h0] = hv;
    }
  }
  __syncthreads();

  // ======== Layer 3: all waves compute the 16x16 out tile; wave 0 stores ========
  {
    float4v acc3 = vzero;
    const _Float16* wb = W3t + ((size_t)e * 16 + l16) * H_DIM;
#pragma unroll
    for (int kb = 0; kb < H_DIM; kb += 32) {
      int kofs = kb + kq;
      half8 afrag = *(const half8*)(wb + kofs);
      half8 bfrag = *(const half8*)&H2s[l16][kofs];
      acc3 = __builtin_amdgcn_mfma_f32_16x16x32_f16(afrag, bfrag, acc3, 0, 0, 0);
    }
    if (wave == 0 && quad < 2 && si < cnt) {
      float4v y;
#pragma unroll
      for (int r = 0; r < 4; ++r) y[r] = acc3[r] + bias3[quad * 4 + r];
      *(float4v*)&out[(size_t)row * DA + quad * 4] = y;
    }
  }
}

extern "C" void kernel_launch(void* const* d_in, const int* in_sizes, int n_in,
                              void* d_out, int out_size, void* d_ws, size_t ws_size,
                              hipStream_t stream) {
  const float* features = (const float*)d_in[0];
  const float* W1 = (const float*)d_in[1];
  const float* b1 = (const float*)d_in[2];
  const float* W2 = (const float*)d_in[3];
  const float* b2 = (const float*)d_in[4];
  const float* W3 = (const float*)d_in[5];
  const float* b3 = (const float*)d_in[6];
  const int* act = (const int*)d_in[7];
  float* out = (float*)d_out;

  char* ws = (char*)d_ws;
  int* counts = (int*)ws;                                   // 256 B
  int* idxbuf = (int*)(ws + 256);                           // 512 KiB
  _Float16* W1t = (_Float16*)(ws + 256 + 524288);           // 2 MiB
  _Float16* W2t = (_Float16*)(ws + 256 + 524288 + 2097152); // 1 MiB
  _Float16* W3t = (_Float16*)(ws + 256 + 524288 + 2097152 + 1048576); // 64 KiB

  hipMemsetAsync(counts, 0, 256, stream);
  k_bucket<<<B_TOTAL / 256, 256, 0, stream>>>(act, counts, idxbuf);
  k_transpose<F_DIM, H_DIM><<<dim3(F_DIM / 32, H_DIM / 32, E_NUM), 256, 0, stream>>>(W1, W1t);
  k_transpose<H_DIM, H_DIM><<<dim3(H_DIM / 32, H_DIM / 32, E_NUM), 256, 0, stream>>>(W2, W2t);
  k_w3prep<<<E_NUM, H_DIM, 0, stream>>>(W3, W3t);
  k_mlp<<<dim3(B_TOTAL / TM, E_NUM), 256, 0, stream>>>(features, W1t, W2t, W3t,
                                                       b1, b2, b3, counts, idxbuf, out);
}

// Round 3
// 143.258 us; speedup vs baseline: 1.4731x; 1.4731x over previous
//
#include <hip/hip_runtime.h>

#define B_TOTAL 16384
#define F_DIM 512
#define H_DIM 256
#define E_NUM 8
#define OUT_COLS 32
#define DA 8
#define TM 32                 // samples per block
#define HSTRIDE (H_DIM + 8)   // 264 halves: rows 16B-aligned

typedef __attribute__((ext_vector_type(8))) _Float16 half8;
typedef __attribute__((ext_vector_type(4))) _Float16 half4;
typedef __attribute__((ext_vector_type(4))) float float4v;

// ---------------- bucket samples by expert (block-aggregated atomics) ----------------
__global__ void k_bucket(const int* __restrict__ act, int* __restrict__ counts,
                         int* __restrict__ idxbuf) {
  __shared__ int wcnt[4][E_NUM];
  __shared__ int wbase[4][E_NUM];
  int t = threadIdx.x;
  int lane = t & 63, wave = t >> 6;
  int b = blockIdx.x * 256 + t;
  int e = act[b] & 7;

  unsigned long long mymask = 0;
#pragma unroll
  for (int v = 0; v < E_NUM; ++v) {
    unsigned long long m = __ballot(e == v);
    if (lane == 0) wcnt[wave][v] = (int)__popcll(m);
    if (e == v) mymask = m;
  }
  int rank = (int)__popcll(mymask & ((1ull << lane) - 1ull));
  __syncthreads();
  if (t < E_NUM) {
    int c0 = wcnt[0][t], c1 = wcnt[1][t], c2 = wcnt[2][t], c3 = wcnt[3][t];
    int base = atomicAdd(&counts[t], c0 + c1 + c2 + c3);
    wbase[0][t] = base;
    wbase[1][t] = base + c0;
    wbase[2][t] = base + c0 + c1;
    wbase[3][t] = base + c0 + c1 + c2;
  }
  __syncthreads();
  idxbuf[e * B_TOTAL + wbase[wave][e] + rank] = b;
}

// ---------------- fused weight prep: transpose W1,W2 (fp32->fp16) + W3 pack ----------------
__global__ void k_prep(const float* __restrict__ W1, const float* __restrict__ W2,
                       const float* __restrict__ W3,
                       _Float16* __restrict__ W1t, _Float16* __restrict__ W2t,
                       _Float16* __restrict__ W3t) {
  __shared__ float tile[32][33];
  int bid = blockIdx.x;
  int tx = threadIdx.x & 31, ty = threadIdx.x >> 5;  // 32x8

  const float* S; _Float16* D; int K, N, k0, n0;
  if (bid < 1024) {            // W1: (512,256) -> (256,512), 128 tiles/expert
    int e = bid >> 7, tt = bid & 127;
    K = F_DIM; N = H_DIM; k0 = (tt >> 3) * 32; n0 = (tt & 7) * 32;
    S = W1 + (size_t)e * F_DIM * H_DIM;
    D = W1t + (size_t)e * H_DIM * F_DIM;
  } else if (bid < 1536) {     // W2: (256,256) -> (256,256), 64 tiles/expert
    int r = bid - 1024;
    int e = r >> 6, tt = r & 63;
    K = H_DIM; N = H_DIM; k0 = (tt >> 3) * 32; n0 = (tt & 7) * 32;
    S = W2 + (size_t)e * H_DIM * H_DIM;
    D = W2t + (size_t)e * H_DIM * H_DIM;
  } else {                     // W3: (256,32) -> (16,256) with rows 8..15 = 0
    int e = bid - 1536;
    int k = threadIdx.x;
#pragma unroll
    for (int o = 0; o < 16; ++o) {
      float v = (o < DA) ? W3[((size_t)e * H_DIM + k) * OUT_COLS + o] : 0.f;
      W3t[((size_t)e * 16 + o) * H_DIM + k] = (_Float16)v;
    }
    return;
  }
#pragma unroll
  for (int r = 0; r < 32; r += 8)
    tile[ty + r][tx] = S[(size_t)(k0 + ty + r) * N + (n0 + tx)];
  __syncthreads();
#pragma unroll
  for (int r = 0; r < 32; r += 8)
    D[(size_t)(n0 + ty + r) * K + (k0 + tx)] = (_Float16)tile[tx][ty + r];
}

// ---------------- gather X rows into bucket-compact fp16 layout ----------------
// Compact row index == slot; expert regions rounded up to 32 rows, pad rows zeroed.
// One wave per row: coalesced 2KB read, 1KB write. Massive row-level parallelism.
__global__ void k_gather(const float* __restrict__ X, const int* __restrict__ counts,
                         const int* __restrict__ idxbuf, _Float16* __restrict__ Xg) {
  int wave = threadIdx.x >> 6, lane = threadIdx.x & 63;
  int slot = blockIdx.x * 4 + wave;

  int base = 0, e = -1, pos = 0, cnt_e = 0;
#pragma unroll
  for (int j = 0; j < E_NUM; ++j) {
    if (e < 0) {
      int c = counts[j];
      int rc = (c + 31) & ~31;
      if (slot < base + rc) { e = j; pos = slot - base; cnt_e = c; }
      else base += rc;
    }
  }
  if (e < 0) return;

  _Float16* dst = Xg + (size_t)slot * F_DIM + lane * 8;
  if (pos < cnt_e) {
    const float* src = X + (size_t)idxbuf[e * B_TOTAL + pos] * F_DIM + lane * 8;
    float4v x0 = *(const float4v*)src;
    float4v x1 = *(const float4v*)(src + 4);
    half8 h;
    h[0] = (_Float16)x0.x; h[1] = (_Float16)x0.y;
    h[2] = (_Float16)x0.z; h[3] = (_Float16)x0.w;
    h[4] = (_Float16)x1.x; h[5] = (_Float16)x1.y;
    h[6] = (_Float16)x1.z; h[7] = (_Float16)x1.w;
    *(half8*)dst = h;
  } else {
    half8 z = {};
    *(half8*)dst = z;
  }
}

// ---------------- fused 3-layer expert MLP ----------------
// Block = (expert, 32-sample tile). 4 waves; wave owns 64 hidden rows (4 m-tiles x 2 s-tiles).
// Depth-2 register prefetch in K-loops keeps ~12 loads in flight per wave.
__global__ __launch_bounds__(256, 3) void k_mlp(
    const _Float16* __restrict__ Xg,
    const _Float16* __restrict__ W1t,
    const _Float16* __restrict__ W2t,
    const _Float16* __restrict__ W3t,
    const float* __restrict__ b1,
    const float* __restrict__ b2,
    const float* __restrict__ b3,
    const int* __restrict__ counts,
    const int* __restrict__ idxbuf,
    float* __restrict__ out)
{
  int e = blockIdx.y;
  int cnt = counts[e];
  int tile0 = blockIdx.x * TM;
  if (tile0 >= cnt) return;

  // compact-region base for this expert
  int xbase = 0;
#pragma unroll
  for (int j = 0; j < E_NUM; ++j)
    if (j < e) xbase += (counts[j] + 31) & ~31;

  __shared__ _Float16 H1s[TM][HSTRIDE];
  __shared__ _Float16 H2s[TM][HSTRIDE];

  int t = threadIdx.x;
  int lane = t & 63;
  int wave = t >> 6;
  int quad = lane >> 4;
  int l16 = lane & 15;
  int hbase = wave * 64;
  int kq = quad * 8;

  const float4v vzero = {0.f, 0.f, 0.f, 0.f};
  float4v acc[4][2];
#pragma unroll
  for (int mt = 0; mt < 4; ++mt)
#pragma unroll
    for (int st = 0; st < 2; ++st) acc[mt][st] = vzero;

  // ======== Layer 1: H1^T[h][s] = sum_k W1t[h][k] * Xg[s][k] ========
  {
    const _Float16* wb = W1t + ((size_t)e * H_DIM + hbase + l16) * F_DIM + kq;
    const _Float16* xb = Xg + ((size_t)(xbase + tile0) + l16) * F_DIM + kq;
    half8 a_p[2][4], b_p[2][2];
#pragma unroll
    for (int p = 0; p < 2; ++p) {
#pragma unroll
      for (int mt = 0; mt < 4; ++mt)
        a_p[p][mt] = *(const half8*)(wb + (size_t)mt * 16 * F_DIM + p * 32);
#pragma unroll
      for (int st = 0; st < 2; ++st)
        b_p[p][st] = *(const half8*)(xb + (size_t)st * 16 * F_DIM + p * 32);
    }
#pragma unroll
    for (int kb = 0; kb < F_DIM; kb += 32) {
      int p = (kb >> 5) & 1;
      half8 a_cur[4], b_cur[2];
#pragma unroll
      for (int mt = 0; mt < 4; ++mt) a_cur[mt] = a_p[p][mt];
#pragma unroll
      for (int st = 0; st < 2; ++st) b_cur[st] = b_p[p][st];
      if (kb + 64 < F_DIM) {
#pragma unroll
        for (int mt = 0; mt < 4; ++mt)
          a_p[p][mt] = *(const half8*)(wb + (size_t)mt * 16 * F_DIM + kb + 64);
#pragma unroll
        for (int st = 0; st < 2; ++st)
          b_p[p][st] = *(const half8*)(xb + (size_t)st * 16 * F_DIM + kb + 64);
      }
#pragma unroll
      for (int mt = 0; mt < 4; ++mt)
#pragma unroll
        for (int st = 0; st < 2; ++st)
          acc[mt][st] = __builtin_amdgcn_mfma_f32_16x16x32_f16(a_cur[mt], b_cur[st], acc[mt][st], 0, 0, 0);
    }
    // epilogue: bias + relu -> H1s[sample][hidden]
#pragma unroll
    for (int mt = 0; mt < 4; ++mt) {
      int h0 = hbase + mt * 16 + quad * 4;
      float4v bb = *(const float4v*)&b1[e * H_DIM + h0];
#pragma unroll
      for (int st = 0; st < 2; ++st) {
        half4 hv;
#pragma unroll
        for (int r = 0; r < 4; ++r) {
          float v = acc[mt][st][r] + bb[r];
          hv[r] = (_Float16)(v > 0.f ? v : 0.f);
        }
        *(half4*)&H1s[st * 16 + l16][h0] = hv;
      }
    }
  }
  __syncthreads();

  // ======== Layer 2: H2^T[h][s] = sum_k W2t[h][k] * H1[s][k] ========
#pragma unroll
  for (int mt = 0; mt < 4; ++mt)
#pragma unroll
    for (int st = 0; st < 2; ++st) acc[mt][st] = vzero;
  {
    const _Float16* wb = W2t + ((size_t)e * H_DIM + hbase + l16) * H_DIM + kq;
    half8 a_p[2][4];
#pragma unroll
    for (int p = 0; p < 2; ++p)
#pragma unroll
      for (int mt = 0; mt < 4; ++mt)
        a_p[p][mt] = *(const half8*)(wb + (size_t)mt * 16 * H_DIM + p * 32);
#pragma unroll
    for (int kb = 0; kb < H_DIM; kb += 32) {
      int p = (kb >> 5) & 1;
      half8 a_cur[4];
#pragma unroll
      for (int mt = 0; mt < 4; ++mt) a_cur[mt] = a_p[p][mt];
      if (kb + 64 < H_DIM) {
#pragma unroll
        for (int mt = 0; mt < 4; ++mt)
          a_p[p][mt] = *(const half8*)(wb + (size_t)mt * 16 * H_DIM + kb + 64);
      }
      half8 b_cur[2];
#pragma unroll
      for (int st = 0; st < 2; ++st)
        b_cur[st] = *(const half8*)&H1s[st * 16 + l16][kb + kq];
#pragma unroll
      for (int mt = 0; mt < 4; ++mt)
#pragma unroll
        for (int st = 0; st < 2; ++st)
          acc[mt][st] = __builtin_amdgcn_mfma_f32_16x16x32_f16(a_cur[mt], b_cur[st], acc[mt][st], 0, 0, 0);
    }
#pragma unroll
    for (int mt = 0; mt < 4; ++mt) {
      int h0 = hbase + mt * 16 + quad * 4;
      float4v bb = *(const float4v*)&b2[e * H_DIM + h0];
#pragma unroll
      for (int st = 0; st < 2; ++st) {
        half4 hv;
#pragma unroll
        for (int r = 0; r < 4; ++r) {
          float v = acc[mt][st][r] + bb[r];
          hv[r] = (_Float16)(v > 0.f ? v : 0.f);
        }
        *(half4*)&H2s[st * 16 + l16][h0] = hv;
      }
    }
  }
  __syncthreads();

  // ======== Layer 3: waves 0,1 each compute one 16-sample out tile ========
  if (wave < 2) {
    float4v acc3 = vzero;
    const _Float16* wb = W3t + ((size_t)e * 16 + l16) * H_DIM + kq;
#pragma unroll
    for (int kb = 0; kb < H_DIM; kb += 32) {
      half8 afrag = *(const half8*)(wb + kb);
      half8 bfrag = *(const half8*)&H2s[wave * 16 + l16][kb + kq];
      acc3 = __builtin_amdgcn_mfma_f32_16x16x32_f16(afrag, bfrag, acc3, 0, 0, 0);
    }
    int si = tile0 + wave * 16 + l16;
    if (quad < 2 && si < cnt) {
      int row = idxbuf[e * B_TOTAL + si];
      float4v bb = *(const float4v*)&b3[e * OUT_COLS + quad * 4];
      float4v y;
#pragma unroll
      for (int r = 0; r < 4; ++r) y[r] = acc3[r] + bb[r];
      *(float4v*)&out[(size_t)row * DA + quad * 4] = y;
    }
  }
}

extern "C" void kernel_launch(void* const* d_in, const int* in_sizes, int n_in,
                              void* d_out, int out_size, void* d_ws, size_t ws_size,
                              hipStream_t stream) {
  const float* features = (const float*)d_in[0];
  const float* W1 = (const float*)d_in[1];
  const float* b1 = (const float*)d_in[2];
  const float* W2 = (const float*)d_in[3];
  const float* b2 = (const float*)d_in[4];
  const float* W3 = (const float*)d_in[5];
  const float* b3 = (const float*)d_in[6];
  const int* act = (const int*)d_in[7];
  float* out = (float*)d_out;

  char* ws = (char*)d_ws;
  int* counts = (int*)ws;                                      // 256 B
  int* idxbuf = (int*)(ws + 256);                              // 512 KiB
  _Float16* W1t = (_Float16*)(ws + 256 + 524288);              // 2 MiB
  _Float16* W2t = (_Float16*)(ws + 256 + 524288 + 2097152);    // 1 MiB
  _Float16* W3t = (_Float16*)(ws + 256 + 524288 + 2097152 + 1048576);  // 64 KiB
  _Float16* Xg  = (_Float16*)(ws + 256 + 524288 + 2097152 + 1048576 + 65536);  // ~17 MiB

  hipMemsetAsync(counts, 0, 256, stream);
  k_bucket<<<B_TOTAL / 256, 256, 0, stream>>>(act, counts, idxbuf);
  k_prep<<<1544, 256, 0, stream>>>(W1, W2, W3, W1t, W2t, W3t);
  k_gather<<<4160, 256, 0, stream>>>(features, counts, idxbuf, Xg);
  k_mlp<<<dim3(B_TOTAL / TM, E_NUM), 256, 0, stream>>>(Xg, W1t, W2t, W3t,
                                                       b1, b2, b3, counts, idxbuf, out);
}